// Round 3
// baseline (783.451 us; speedup 1.0000x reference)
//
#include <hip/hip_runtime.h>
#include <hip/hip_bf16.h>

// Problem constants: N=64 batch, C=23 chromosomes, G=20000 genes, H=64 hidden.
// x:(N,G,H) f32, chrom_mat:(C,G) one-hot f32, attention:(C,H) f32. out:(N,C,H) f32.
#define N_ 64
#define C_ 23
#define G_ 20000
#define H_ 64
#define SLICES 32                         // gene slices per batch item
#define GPB ((G_ + SLICES - 1) / SLICES)  // genes per block = 625
#define PAD 66                            // LDS row stride in words (even, !=0 mod 32/4 pattern)

// ---------------------------------------------------------------------------
// Kernel 1: recover assign[g] = index of the nonzero in one-hot chrom_mat[:,g].
__global__ void assign_kernel(const float* __restrict__ chrom,
                              int* __restrict__ assign) {
    int g = blockIdx.x * blockDim.x + threadIdx.x;
    if (g >= G_) return;
    int c_found = 0;
    #pragma unroll
    for (int c = 0; c < C_; ++c) {
        if (chrom[c * G_ + g] != 0.f) c_found = c;
    }
    assign[g] = c_found;
}

// ---------------------------------------------------------------------------
// Kernel 2 (main): block = (n, contiguous gene slice). x read as pure linear
// stream: 32-lane group per gene, float2 per lane (256B/gene, wave covers 2
// consecutive genes = 512B contiguous). Accumulators for all 23 chromosomes
// in LDS via native ds_add_f32 (plain atomicAdd — NOT unsafeAtomicAdd, which
// lowered to a flat atomic on LDS pointers and serialized round 2 to 441us).
// Lane stride is 2 words -> attn reads ~2-way banked (free), acc atomics
// ~4-way. One global atomic flush per block.
__global__ __launch_bounds__(256) void main_stream(
    const float* __restrict__ x,        // (N,G,H)
    const float* __restrict__ attn,     // (C,H)
    const int* __restrict__ assign,     // (G)
    float* __restrict__ acc,            // (N,C,H)  zero-initialized
    float* __restrict__ denom)          // (N,C)    zero-initialized
{
    __shared__ float attn_s[C_ * PAD];
    __shared__ float acc_s[C_ * PAD];
    __shared__ float den_s[C_];
    __shared__ int   asg_s[GPB];

    int n = blockIdx.x / SLICES;
    int s = blockIdx.x % SLICES;
    int lo = s * GPB;
    int hi = min(lo + GPB, G_);
    int cnt = hi - lo;

    int tid = threadIdx.x;
    // Stage attention (padded rows), zero accumulators, stage assign slice.
    for (int i = tid; i < C_ * PAD; i += 256) {
        int r = i / PAD, col = i % PAD;
        attn_s[i] = (col < H_) ? attn[r * H_ + col] : 0.f;
        acc_s[i]  = 0.f;
    }
    if (tid < C_) den_s[tid] = 0.f;
    for (int i = tid; i < cnt; i += 256) {
        asg_s[i] = assign[lo + i];
    }
    __syncthreads();

    int sub = tid & 31;   // lane within 32-lane gene group: h = 2*sub, 2*sub+1
    int grp = tid >> 5;   // gene group id within block, 0..7

    const float2* xrow_base = (const float2*)(x + (size_t)n * G_ * H_);

    #pragma unroll 4
    for (int g = lo + grp; g < hi; g += 8) {
        int c = asg_s[g - lo];                               // broadcast in group
        const float2 x2 = xrow_base[(size_t)g * (H_ / 2) + sub];
        const float2 a2 = ((const float2*)(attn_s + c * PAD))[sub];
        float part = a2.x * x2.x + a2.y * x2.y;
        // reduce dot over the 32 lanes of this gene group (xor stays in-group)
        part += __shfl_xor(part, 1);
        part += __shfl_xor(part, 2);
        part += __shfl_xor(part, 4);
        part += __shfl_xor(part, 8);
        part += __shfl_xor(part, 16);
        // att == part (one-hot value is exactly 1.0); mask = (att != 0)
        float w = 0.f;
        if (part != 0.f) {
            float lr = (part >= 0.f) ? part : 0.2f * part;
            w = __expf(lr);
        }
        float* ap = acc_s + c * PAD + sub * 2;
        atomicAdd(ap + 0, w * x2.x);
        atomicAdd(ap + 1, w * x2.y);
        if (sub == 0) atomicAdd(&den_s[c], w);
    }
    __syncthreads();

    // Flush block partials to global accumulators (plain atomicAdd, f32).
    float* accg = acc + (size_t)n * C_ * H_;
    for (int i = tid; i < C_ * H_; i += 256) {
        int r = i >> 6, col = i & 63;
        float v = acc_s[r * PAD + col];
        if (v != 0.f) atomicAdd(accg + i, v);
    }
    if (tid < C_) {
        float v = den_s[tid];
        if (v != 0.f) atomicAdd(denom + n * C_ + tid, v);
    }
}

// ---------------------------------------------------------------------------
// Kernel 3: out = acc / max(denom, 1e-10)
__global__ void finalize_kernel(const float* __restrict__ acc,
                                const float* __restrict__ denom,
                                float* __restrict__ out) {
    int i = blockIdx.x * blockDim.x + threadIdx.x;
    if (i >= N_ * C_ * H_) return;
    int nc = i >> 6;  // / H_
    float d = fmaxf(denom[nc], 1e-10f);
    out[i] = acc[i] / d;
}

// ---------------------------------------------------------------------------
extern "C" void kernel_launch(void* const* d_in, const int* in_sizes, int n_in,
                              void* d_out, int out_size, void* d_ws, size_t ws_size,
                              hipStream_t stream) {
    const float* x     = (const float*)d_in[0];   // N*G*H
    const float* chrom = (const float*)d_in[1];   // C*G
    const float* attn  = (const float*)d_in[2];   // C*H
    float* out = (float*)d_out;

    // Workspace layout:
    //   acc    : N*C*H floats   (zeroed)
    //   denom  : N*C   floats   (zeroed)
    //   assign : G     ints     (fully overwritten)
    float* acc    = (float*)d_ws;
    float* denom  = acc + (size_t)N_ * C_ * H_;
    int*   assign = (int*)(denom + (size_t)N_ * C_);

    size_t zero_bytes = ((size_t)N_ * C_ * H_ + (size_t)N_ * C_) * sizeof(float);
    hipMemsetAsync(d_ws, 0, zero_bytes, stream);

    assign_kernel<<<(G_ + 255) / 256, 256, 0, stream>>>(chrom, assign);

    main_stream<<<N_ * SLICES, 256, 0, stream>>>(x, attn, assign, acc, denom);

    finalize_kernel<<<(N_ * C_ * H_ + 255) / 256, 256, 0, stream>>>(acc, denom, out);
}

// Round 4
// 533.465 us; speedup vs baseline: 1.4686x; 1.4686x over previous
//
#include <hip/hip_runtime.h>
#include <hip/hip_bf16.h>

// Problem constants: N=64 batch, C=23 chromosomes, G=20000 genes, H=64 hidden.
// x:(N,G,H) f32, chrom_mat:(C,G) one-hot f32, attention:(C,H) f32. out:(N,C,H) f32.
#define N_ 64
#define C_ 23
#define G_ 20000
#define H_ 64
#define S_ 4   // slices per (n,c) in the main pass

// 16-lane rotate-add allreduce step via DPP (row_ror) — pure VALU, no LDS pipe.
// CTRL: 0x120|n = row_ror:n (rotation within each 16-lane row).
template <int CTRL>
__device__ __forceinline__ float ror_add(float v) {
    int r = __builtin_amdgcn_update_dpp(0, __float_as_int(v), CTRL, 0xf, 0xf, true);
    return v + __int_as_float(r);
}

// ---------------------------------------------------------------------------
// Kernel 1: assign[g] = argmax_c one-hot + histogram.
__global__ void assign_kernel(const float* __restrict__ chrom,
                              int* __restrict__ assign,
                              int* __restrict__ counts) {
    int g = blockIdx.x * blockDim.x + threadIdx.x;
    if (g >= G_) return;
    int c_found = 0;
    #pragma unroll
    for (int c = 0; c < C_; ++c) {
        if (chrom[c * G_ + g] != 0.f) c_found = c;
    }
    assign[g] = c_found;
    atomicAdd(&counts[c_found], 1);
}

// ---------------------------------------------------------------------------
// Kernel 2: exclusive scan over 23 buckets.
__global__ void scan_kernel(const int* __restrict__ counts,
                            int* __restrict__ offsets,
                            int* __restrict__ cursors) {
    if (threadIdx.x == 0 && blockIdx.x == 0) {
        int run = 0;
        for (int c = 0; c < C_; ++c) {
            offsets[c] = run;
            cursors[c] = run;
            run += counts[c];
        }
        offsets[C_] = run;
    }
}

// ---------------------------------------------------------------------------
// Kernel 3: counting-sort scatter of gene ids by chromosome.
__global__ void scatter_kernel(const int* __restrict__ assign,
                               int* __restrict__ cursors,
                               int* __restrict__ sorted_g) {
    int g = blockIdx.x * blockDim.x + threadIdx.x;
    if (g >= G_) return;
    int c = assign[g];
    int pos = atomicAdd(&cursors[c], 1);
    sorted_g[pos] = g;
}

// ---------------------------------------------------------------------------
// Kernel 4 (main): block = (n, c, slice). Chromosome uniform per block ->
// attention row and w*x accumulator stay in REGISTERS; the 16-lane dot
// reduction is 4 DPP rotate-adds (VALU). ZERO LDS-pipe ops in the loop —
// rounds 2/3 proved in-loop ds_swizzle/ds_atomic latency chains serialize
// everything (469us at 5% HBM, 6% VALU).
__global__ __launch_bounds__(256) void main_pass(
    const float* __restrict__ x,        // (N,G,H)
    const float* __restrict__ attn,     // (C,H)
    const int* __restrict__ offsets,    // C+1
    const int* __restrict__ sorted_g,   // G
    float* __restrict__ acc,            // (N,C,H)  zero-initialized
    float* __restrict__ denom)          // (N,C)    zero-initialized
{
    int b = blockIdx.x;
    int s = b % S_; b /= S_;
    int c = b % C_; b /= C_;
    int n = b;

    int beg = offsets[c];
    int end = offsets[c + 1];
    int cnt = end - beg;
    int L   = (cnt + S_ - 1) / S_;
    int lo  = beg + s * L;
    int hi  = min(beg + (s + 1) * L, end);

    int tid = threadIdx.x;
    int sub = tid & 15;   // lane in 16-lane gene group: h = 4*sub..4*sub+3
    int grp = tid >> 4;   // gene group id within block, 0..15

    const float4 a4 = ((const float4*)(attn + c * H_))[sub];

    float4 accv = make_float4(0.f, 0.f, 0.f, 0.f);
    float dsum = 0.f;

    const float* xb = x + (size_t)n * G_ * H_;

    #pragma unroll 2
    for (int p = lo + grp; p < hi; p += 16) {
        int g = sorted_g[p];
        const float4 x4 = ((const float4*)(xb + (size_t)g * H_))[sub];
        float part = fmaf(a4.x, x4.x, fmaf(a4.y, x4.y, fmaf(a4.z, x4.z, a4.w * x4.w)));
        // 16-lane allreduce: rotate-add by 8,4,2,1 (row_ror DPP) — all lanes
        // end with the full dot product. No LDS pipe involvement.
        part = ror_add<0x128>(part);
        part = ror_add<0x124>(part);
        part = ror_add<0x122>(part);
        part = ror_add<0x121>(part);
        float w = 0.f;
        if (part != 0.f) {
            float lr = (part >= 0.f) ? part : 0.2f * part;
            w = __expf(lr);
        }
        accv.x = fmaf(w, x4.x, accv.x);
        accv.y = fmaf(w, x4.y, accv.y);
        accv.z = fmaf(w, x4.z, accv.z);
        accv.w = fmaf(w, x4.w, accv.w);
        dsum += w;   // identical across the 16 lanes of this group
    }

    // Reduce across the 4 gene-groups within the wave (one-time cost).
    #pragma unroll
    for (int m = 16; m <= 32; m <<= 1) {
        accv.x += __shfl_xor(accv.x, m);
        accv.y += __shfl_xor(accv.y, m);
        accv.z += __shfl_xor(accv.z, m);
        accv.w += __shfl_xor(accv.w, m);
        dsum   += __shfl_xor(dsum, m);
    }

    // One wave-partial flush: atomics into global accumulator.
    int lane = tid & 63;
    float* accp = acc + ((size_t)n * C_ + c) * H_;
    if (lane < 16) {
        atomicAdd(accp + sub * 4 + 0, accv.x);
        atomicAdd(accp + sub * 4 + 1, accv.y);
        atomicAdd(accp + sub * 4 + 2, accv.z);
        atomicAdd(accp + sub * 4 + 3, accv.w);
        if (sub == 0) atomicAdd(denom + n * C_ + c, dsum);
    }
}

// ---------------------------------------------------------------------------
// Kernel 5: out = acc / max(denom, 1e-10)
__global__ void finalize_kernel(const float* __restrict__ acc,
                                const float* __restrict__ denom,
                                float* __restrict__ out) {
    int i = blockIdx.x * blockDim.x + threadIdx.x;
    if (i >= N_ * C_ * H_) return;
    int nc = i >> 6;  // / H_
    float d = fmaxf(denom[nc], 1e-10f);
    out[i] = acc[i] / d;
}

// ---------------------------------------------------------------------------
extern "C" void kernel_launch(void* const* d_in, const int* in_sizes, int n_in,
                              void* d_out, int out_size, void* d_ws, size_t ws_size,
                              hipStream_t stream) {
    const float* x     = (const float*)d_in[0];   // N*G*H
    const float* chrom = (const float*)d_in[1];   // C*G
    const float* attn  = (const float*)d_in[2];   // C*H
    float* out = (float*)d_out;

    // Workspace layout:
    //   acc    : N*C*H floats   (zeroed)
    //   denom  : N*C   floats   (zeroed)
    //   counts : C     ints     (zeroed)
    //   cursors: C     ints     (overwritten by scan)
    //   offsets: C+1   ints     (overwritten by scan)
    //   assign : G     ints     (fully overwritten)
    //   sorted : G     ints     (fully overwritten)
    float* acc    = (float*)d_ws;
    float* denom  = acc + (size_t)N_ * C_ * H_;
    int*   counts  = (int*)(denom + (size_t)N_ * C_);
    int*   cursors = counts + C_;
    int*   offsets = cursors + C_;
    int*   assign  = offsets + (C_ + 1);
    int*   sorted  = assign + G_;

    size_t zero_bytes = ((size_t)N_ * C_ * H_ + (size_t)N_ * C_ + C_) * sizeof(float);
    hipMemsetAsync(d_ws, 0, zero_bytes, stream);

    int gb = (G_ + 255) / 256;
    assign_kernel<<<gb, 256, 0, stream>>>(chrom, assign, counts);
    scan_kernel<<<1, 64, 0, stream>>>(counts, offsets, cursors);
    scatter_kernel<<<gb, 256, 0, stream>>>(assign, cursors, sorted);

    main_pass<<<N_ * C_ * S_, 256, 0, stream>>>(x, attn, offsets, sorted, acc, denom);

    finalize_kernel<<<(N_ * C_ * H_ + 255) / 256, 256, 0, stream>>>(acc, denom, out);
}